// Round 13
// baseline (357.497 us; speedup 1.0000x reference)
//
#include <hip/hip_runtime.h>
#include <hip/hip_bf16.h>
#include <cstdint>

typedef unsigned short u16;
typedef __attribute__((ext_vector_type(8))) __bf16 bf16x8;
typedef __attribute__((ext_vector_type(4))) float f32x4;
typedef __attribute__((ext_vector_type(8))) u16 us8;
typedef __attribute__((ext_vector_type(4))) u16 us4;

__device__ __forceinline__ float bf2f(u16 u) {
    return __uint_as_float(((unsigned int)u) << 16);
}
__device__ __forceinline__ u16 f2bf(float f) {
    unsigned int u = __float_as_uint(f);
    unsigned int r = (u + 0x7fffu + ((u >> 16) & 1u)) >> 16;
    return (u16)r;
}

__device__ __forceinline__ void gload_lds16(const void* src, void* dst) {
    __builtin_amdgcn_global_load_lds(
        (const __attribute__((address_space(1))) void*)src,
        (__attribute__((address_space(3))) void*)dst,
        16, 0, 0);
}

// ---------------------------------------------------------------------------
// Weight prep (bf16, transposed: BT[n][k] contiguous along K):
//  BT1 (1024x512): rows j<512 = mW1_top^T ; rows j>=512 = mW1_bot^T
//  BT4 (512x512)  = uW2^T
//  A_w (512x512)  : A_w[j][l] = uW1[512+l][j]   (GEMM-A for Wc^T)
//  B_w (512x512)  : mW2 as-is
//  BTx (512x1024) : k<512 = uW1_top^T; k>=512 = Wc^T (filled by wc gemm)
//  bias1024       : [mb1 | 0]
// ---------------------------------------------------------------------------
__global__ void prep_weights(const float* __restrict__ mW1, const float* __restrict__ mW2,
                             const float* __restrict__ uW1, const float* __restrict__ uW2,
                             const float* __restrict__ mb1,
                             u16* __restrict__ BT1, u16* __restrict__ BT4,
                             u16* __restrict__ A_w, u16* __restrict__ B_w,
                             u16* __restrict__ BTx, float* __restrict__ bias1024)
{
    int tid = blockIdx.x * 256 + threadIdx.x;           // [0, 524288)
    if (tid < 1024 * 512) {
        int j = tid >> 9, k = tid & 511;
        float v = (j < 512) ? mW1[(size_t)k * 512 + j]
                            : mW1[(size_t)(512 + k) * 512 + (j - 512)];
        BT1[tid] = f2bf(v);
    }
    if (tid < 512 * 512) {
        int j = tid >> 9, k = tid & 511;
        BT4[tid] = f2bf(uW2[(size_t)k * 512 + j]);
        A_w[tid] = f2bf(uW1[(size_t)(512 + k) * 512 + j]);
        B_w[tid] = f2bf(mW2[tid]);
        BTx[(size_t)j * 1024 + k] = f2bf(uW1[(size_t)k * 512 + j]);
    }
    if (tid < 1024) bias1024[tid] = (tid < 512) ? mb1[tid] : 0.f;
}

// biasx[j] = ub1[j] + sum_l mb2[l] * uW1[512+l][j]   (one wave per j)
__global__ void prep_biasx(const float* __restrict__ ub1, const float* __restrict__ mb2,
                           const float* __restrict__ uW1, float* __restrict__ biasx)
{
    int wv = threadIdx.x >> 6, lane = threadIdx.x & 63;
    int j = blockIdx.x * 4 + wv;
    if (j >= 512) return;
    float s = 0.f;
    for (int l = lane; l < 512; l += 64)
        s += mb2[l] * uW1[(size_t)(512 + l) * 512 + j];
#pragma unroll
    for (int off = 32; off; off >>= 1) s += __shfl_xor(s, off, 64);
    if (lane == 0) biasx[j] = ub1[j] + s;
}

// Cast x (f32, M x 512) into cols [0,512) of XS (bf16, M x 1024)
__global__ void cast_x(const float* __restrict__ x, u16* __restrict__ XS, int total4)
{
    int i = blockIdx.x * 256 + threadIdx.x;
    if (i >= total4) return;
    int r = i >> 7, cg = i & 127;
    float4 v = ((const float4*)x)[i];
    us4 o = { f2bf(v.x), f2bf(v.y), f2bf(v.z), f2bf(v.w) };
    *(us4*)(XS + (size_t)r * 1024 + cg * 4) = o;
}

// ---------------------------------------------------------------------------
// GEMM: C[M,N] = A[M,K] (bf16, lda) @ BT[N][K] (bf16, ldb)
// R11 sync discipline VERBATIM (triple-buffer, depth-2 counted vmcnt, single
// barrier/step, row-local XOR swizzle = 0 conflicts). ONE change vs R11/R12:
// WAVE TILE 128x64 (block 256x128, 4 waves, acc[8][4]) — 12 ds_read_b128
// feed 32 MFMA (was 8:16), cutting LDS-pipe demand per FLOP 25% so the
// per-CU LDS read pipe (was the largest term: ~1536cy vs MFMA 1240cy/step)
// drops below MFMA. Staging: 6 gload_lds16/thread/tile (A:4, B:2) ->
// vmcnt(6) = tile t landed, t+1's 6 in flight.
// ---------------------------------------------------------------------------
template<int OUTF32, int DOSILU, int DOBIAS, int DORES>
__global__ __launch_bounds__(256, 2)
void gemm_bt(const u16* __restrict__ A, int lda,
             const u16* __restrict__ Bt, int ldb,
             u16* __restrict__ Cb, float* __restrict__ Cf, int ldc,
             const float* __restrict__ bias,
             const u16* __restrict__ xres, const float* __restrict__ lat,
             const float* __restrict__ ub2v, int Nn, int M, int K)
{
    __shared__ __align__(16) u16 lA[3][256 * 32];   // 3 x 16 KB
    __shared__ __align__(16) u16 lB[3][128 * 32];   // 3 x 8 KB

    // T1: XCD-chunked bijective remap (m204)
    const int gx  = gridDim.x;
    const int nwg = gx * (int)gridDim.y;
    int flat = blockIdx.y * gx + blockIdx.x;
    {
        int q = nwg >> 3, r = nwg & 7;
        int xcd = flat & 7, jj = flat >> 3;
        flat = (xcd < r ? xcd * (q + 1) : r * (q + 1) + (xcd - r) * q) + jj;
    }
    const int m0 = (flat / gx) * 256;
    const int n0 = (flat % gx) * 128;

    const int tid  = threadIdx.x;
    const int wid  = tid >> 6;          // 0..3
    const int lane = tid & 63;
    const int lr   = lane & 15;
    const int h    = lane >> 4;
    const int wr   = wid >> 1;          // 0..1  (M half: 128 rows/wave)
    const int wc   = wid & 1;           // 0..1  (N half: 64 cols/wave)
    const int sw   = (lr >> 1) & 3;     // read-side swizzle (= (row>>1)&3)
    const int hs   = (h ^ sw) * 8;      // swizzled chunk offset (u16 units)

    f32x4 acc[8][4];
#pragma unroll
    for (int i = 0; i < 8; ++i)
#pragma unroll
        for (int j = 0; j < 4; ++j)
            acc[i][j] = (f32x4){0.f, 0.f, 0.f, 0.f};

    const int NT = K >> 5;

    // Staging (6 loads/thread/tile; 256 threads). Chunk (row, slot):
    // LDS [row][slot*16B] linear dest; global chunk = slot ^ ((row>>1)&3)
    // = (tid&3)^((tid>>3)&3) — row-local permute, coalescing intact
    // (4 consecutive tids cover one contiguous 64B row segment).
    const int srow4 = tid >> 2;                              // 0..63
    const int csrc  = ((tid & 3) ^ ((tid >> 3) & 3)) * 8;    // u16 offset

    auto stage = [&](int t, int buf) {
        const int k0 = t << 5;
#pragma unroll
        for (int l = 0; l < 4; ++l) {            // A: 256 rows
            int grow = m0 + l * 64 + srow4; grow = grow < M ? grow : M - 1;
            gload_lds16(A + (size_t)grow * lda + k0 + csrc,
                        &lA[buf][(l * 256 + tid) * 8]);
        }
#pragma unroll
        for (int l = 0; l < 2; ++l) {            // B: 128 rows
            int row = l * 64 + srow4;
            gload_lds16(Bt + (size_t)(n0 + row) * ldb + k0 + csrc,
                        &lB[buf][(l * 256 + tid) * 8]);
        }
    };

    // prologue: tiles 0 and 1 in flight (12 outstanding VMEM/thread)
    stage(0, 0);
    stage(1, 1);

    for (int t = 0; t < NT; ++t) {
        const int buf = t % 3;
        if (t + 1 < NT) {
            // outstanding: tiles t, t+1 (12). Wait tile t; t+1 keeps flying.
            asm volatile("s_waitcnt vmcnt(6)" ::: "memory");
        } else {
            asm volatile("s_waitcnt vmcnt(0)" ::: "memory");
        }
        __builtin_amdgcn_sched_barrier(0);
        __builtin_amdgcn_s_barrier();         // tile t visible; (t-1)%3 free
        __builtin_amdgcn_sched_barrier(0);

        if (t + 2 < NT) stage(t + 2, (t + 2) % 3);

        bf16x8 af[8], bfr[4];
#pragma unroll
        for (int j = 0; j < 4; ++j)
            bfr[j] = *(const bf16x8*)&lB[buf][(wc * 64 + j * 16 + lr) * 32 + hs];
#pragma unroll
        for (int i = 0; i < 8; ++i)
            af[i]  = *(const bf16x8*)&lA[buf][(wr * 128 + i * 16 + lr) * 32 + hs];

#pragma unroll
        for (int i = 0; i < 8; ++i)
#pragma unroll
            for (int j = 0; j < 4; ++j)
                acc[i][j] = __builtin_amdgcn_mfma_f32_16x16x32_bf16(af[i], bfr[j], acc[i][j], 0, 0, 0);
        // no 2nd barrier: ds_reads retire before next step's barrier via the
        // compiler's lgkmcnt-before-MFMA; buffer reuse is 3 steps away.
    }

    float bv[4] = {0.f, 0.f, 0.f, 0.f};
    if (DOBIAS) {
#pragma unroll
        for (int j = 0; j < 4; ++j) bv[j] = bias[n0 + wc * 64 + j * 16 + lr];
    }
    // D layout (m89-verified): col = lane&15, row = 4*(lane>>4) + reg
#pragma unroll
    for (int i = 0; i < 8; ++i) {
#pragma unroll
        for (int rj = 0; rj < 4; ++rj) {
            int grow = m0 + wr * 128 + i * 16 + 4 * h + rj;
            if (grow >= M) continue;
            size_t ro = (size_t)grow * ldc;
            size_t xo = 0, lo = 0;
            if (DORES) {
                int nn = grow % Nn;
                xo = (size_t)grow * 1024;      // XS row (bf16 x in cols 0..511)
                lo = (size_t)nn * 512;
            }
#pragma unroll
            for (int j = 0; j < 4; ++j) {
                int gcol = n0 + wc * 64 + j * 16 + lr;
                float v = acc[i][j][rj] + bv[j];
                if (DOSILU) v = v * __builtin_amdgcn_rcpf(1.f + __expf(-v));
                if (DORES)
                    v += bf2f(xres[xo + gcol]) + lat[lo + gcol] + ub2v[gcol];
                if (OUTF32) Cf[ro + gcol] = v;
                else        Cb[ro + gcol] = f2bf(v);
            }
        }
    }
}

// ---------------------------------------------------------------------------
// S[row] = (1/8) * sum_k silu(c_projb[row] + n_proj[b, knn[n,k]])
// (mb1 folded into c_proj via G1 bias.)  Writes cols 512.. of XS.
// ---------------------------------------------------------------------------
__global__ void gather_silu_mean(const u16* __restrict__ P, const int* __restrict__ knn,
                                 u16* __restrict__ XS, int Nn, int M)
{
    int wid = threadIdx.x >> 6, lane = threadIdx.x & 63;
    int row = blockIdx.x * 4 + wid;
    if (row >= M) return;
    int b = row / Nn, n = row - b * Nn;
    int c0 = lane * 8;

    int idx[8];
#pragma unroll
    for (int k = 0; k < 8; ++k) idx[k] = knn[n * 8 + k];

    us8 cu = *(const us8*)(P + (size_t)row * 1024 + c0);
    const u16* Pn = P + (size_t)b * Nn * 1024 + 512 + c0;
    us8 nb[8];
#pragma unroll
    for (int k = 0; k < 8; ++k) nb[k] = *(const us8*)(Pn + (size_t)idx[k] * 1024);

    float base[8], accv[8];
#pragma unroll
    for (int i = 0; i < 8; ++i) { base[i] = bf2f(cu[i]); accv[i] = 0.f; }

#pragma unroll
    for (int k = 0; k < 8; ++k)
#pragma unroll
        for (int i = 0; i < 8; ++i) {
            float pv = base[i] + bf2f(nb[k][i]);
            accv[i] += pv * __builtin_amdgcn_rcpf(1.f + __expf(-pv));
        }

    us8 o;
#pragma unroll
    for (int i = 0; i < 8; ++i) o[i] = f2bf(accv[i] * 0.125f);
    *(us8*)(XS + (size_t)row * 1024 + 512 + c0) = o;
}

// ---------------------------------------------------------------------------
// LN: reads bf16 pre-LN rows (Yt), writes f32 output Y.
// ---------------------------------------------------------------------------
__global__ void ln_fuse(const u16* __restrict__ Yt, float* __restrict__ Y,
                        const float* __restrict__ g, const float* __restrict__ bta,
                        int M)
{
    int wid = threadIdx.x >> 6, lane = threadIdx.x & 63;
    int row = blockIdx.x * 4 + wid;
    if (row >= M) return;
    int c0 = lane * 8;

    us8 u = *(const us8*)(Yt + (size_t)row * 512 + c0);
    float v[8];
#pragma unroll
    for (int i = 0; i < 8; ++i) v[i] = bf2f(u[i]);

    float s = 0.f;
#pragma unroll
    for (int i = 0; i < 8; ++i) s += v[i];
#pragma unroll
    for (int off = 32; off > 0; off >>= 1) s += __shfl_xor(s, off, 64);
    float mu = s * (1.f / 512.f);

    float q = 0.f;
#pragma unroll
    for (int i = 0; i < 8; ++i) { float d = v[i] - mu; q += d * d; }
#pragma unroll
    for (int off = 32; off > 0; off >>= 1) q += __shfl_xor(q, off, 64);
    float inv = rsqrtf(q * (1.f / 512.f) + 1e-5f);

    float* yr = Y + (size_t)row * 512 + c0;
#pragma unroll
    for (int i = 0; i < 8; ++i) yr[i] = (v[i] - mu) * inv * g[c0 + i] + bta[c0 + i];
}

extern "C" void kernel_launch(void* const* d_in, const int* in_sizes, int n_in,
                              void* d_out, int out_size, void* d_ws, size_t ws_size,
                              hipStream_t stream)
{
    const float* x   = (const float*)d_in[0];
    const float* lat = (const float*)d_in[1];
    const int*   knn = (const int*)d_in[2];
    const float* mW1 = (const float*)d_in[3];
    const float* mb1 = (const float*)d_in[4];
    const float* mW2 = (const float*)d_in[5];
    const float* mb2 = (const float*)d_in[6];
    const float* uW1 = (const float*)d_in[7];
    const float* ub1 = (const float*)d_in[8];
    const float* uW2 = (const float*)d_in[9];
    const float* ub2 = (const float*)d_in[10];
    const float* lng = (const float*)d_in[11];
    const float* lnb = (const float*)d_in[12];

    const int Nn = 10242;
    const int M  = 4 * Nn;       // 40968

    char* ws = (char*)d_ws;
    u16* BT1 = (u16*)ws; ws += (size_t)1024 * 512 * 2;
    u16* BTx = (u16*)ws; ws += (size_t)512 * 1024 * 2;
    u16* BT4 = (u16*)ws; ws += (size_t)512 * 512 * 2;
    u16* A_w = (u16*)ws; ws += (size_t)512 * 512 * 2;
    u16* B_w = (u16*)ws; ws += (size_t)512 * 512 * 2;
    float* bias1024 = (float*)ws; ws += 1024 * 4;
    float* biasx    = (float*)ws; ws += 512 * 4;
    u16* XS = (u16*)ws; ws += (size_t)M * 1024 * 2;    // [x_bf16 | S]
    u16* P  = (u16*)ws; ws += (size_t)M * 1024 * 2;    // [c_proj+mb1 | n_proj]
    u16* T  = (u16*)ws; ws += (size_t)M * 512 * 2;     // silu(u-pre)
    u16* Yt = P;                    // P dead after gather; reuse for pre-LN
    float* Y = (float*)d_out;

    const int MB = (M + 255) / 256;  // 161

    prep_weights<<<2048, 256, 0, stream>>>(mW1, mW2, uW1, uW2, mb1,
                                           BT1, BT4, A_w, B_w, BTx, bias1024);
    prep_biasx<<<128, 256, 0, stream>>>(ub1, mb2, uW1, biasx);
    cast_x<<<(M * 512 / 4 + 255) / 256, 256, 0, stream>>>(x, XS, M * 512 / 4);

    // Wc^T -> BTx cols 512..1023  (M=512, N=512, K=512)
    gemm_bt<0, 0, 0, 0><<<dim3(4, 2), 256, 0, stream>>>(
        A_w, 512, B_w, 512, BTx + 512, nullptr, 1024,
        nullptr, nullptr, nullptr, nullptr, 0, 512, 512);

    // G1: P = x @ [mW1_top | mW1_bot] + [mb1 | 0]   (M x 1024, K=512)
    gemm_bt<0, 0, 1, 0><<<dim3(8, MB), 256, 0, stream>>>(
        XS, 1024, BT1, 512, P, nullptr, 1024,
        bias1024, nullptr, nullptr, nullptr, 0, M, 512);

    gather_silu_mean<<<(M + 3) / 4, 256, 0, stream>>>(P, knn, XS, Nn, M);

    // Gx: T = silu([x|S] @ [uW1_top; Wc] + biasx)   (M x 512, K=1024)
    gemm_bt<0, 1, 1, 0><<<dim3(4, MB), 256, 0, stream>>>(
        XS, 1024, BTx, 1024, T, nullptr, 512,
        biasx, nullptr, nullptr, nullptr, 0, M, 1024);

    // G4: Yt = bf16(T @ uW2 + x + lat + ub2)   (pre-LN, bf16 into P's buffer)
    gemm_bt<0, 0, 0, 1><<<dim3(4, MB), 256, 0, stream>>>(
        T, 512, BT4, 512, Yt, nullptr, 512,
        nullptr, XS, lat, ub2, Nn, M, 512);

    ln_fuse<<<(M + 3) / 4, 256, 0, stream>>>(Yt, Y, lng, lnb, M);
}

// Round 14
// 346.872 us; speedup vs baseline: 1.0306x; 1.0306x over previous
//
#include <hip/hip_runtime.h>
#include <hip/hip_bf16.h>
#include <cstdint>

typedef unsigned short u16;
typedef __attribute__((ext_vector_type(8))) __bf16 bf16x8;
typedef __attribute__((ext_vector_type(4))) float f32x4;
typedef __attribute__((ext_vector_type(8))) u16 us8;
typedef __attribute__((ext_vector_type(4))) u16 us4;

__device__ __forceinline__ float bf2f(u16 u) {
    return __uint_as_float(((unsigned int)u) << 16);
}
__device__ __forceinline__ u16 f2bf(float f) {
    unsigned int u = __float_as_uint(f);
    unsigned int r = (u + 0x7fffu + ((u >> 16) & 1u)) >> 16;
    return (u16)r;
}

__device__ __forceinline__ void gload_lds16(const void* src, void* dst) {
    __builtin_amdgcn_global_load_lds(
        (const __attribute__((address_space(1))) void*)src,
        (__attribute__((address_space(3))) void*)dst,
        16, 0, 0);
}

// ---------------------------------------------------------------------------
// Weight prep (bf16, transposed: BT[n][k] contiguous along K):
//  BT1 (1024x512): rows j<512 = mW1_top^T ; rows j>=512 = mW1_bot^T
//  BT4 (512x512)  = uW2^T
//  A_w (512x512)  : A_w[j][l] = uW1[512+l][j]   (GEMM-A for Wc^T)
//  B_w (512x512)  : mW2 as-is
//  BTx (512x1024) : k<512 = uW1_top^T; k>=512 = Wc^T (filled by wc gemm)
//  bias1024       : [mb1 | 0]
// ---------------------------------------------------------------------------
__global__ void prep_weights(const float* __restrict__ mW1, const float* __restrict__ mW2,
                             const float* __restrict__ uW1, const float* __restrict__ uW2,
                             const float* __restrict__ mb1,
                             u16* __restrict__ BT1, u16* __restrict__ BT4,
                             u16* __restrict__ A_w, u16* __restrict__ B_w,
                             u16* __restrict__ BTx, float* __restrict__ bias1024)
{
    int tid = blockIdx.x * 256 + threadIdx.x;           // [0, 524288)
    if (tid < 1024 * 512) {
        int j = tid >> 9, k = tid & 511;
        float v = (j < 512) ? mW1[(size_t)k * 512 + j]
                            : mW1[(size_t)(512 + k) * 512 + (j - 512)];
        BT1[tid] = f2bf(v);
    }
    if (tid < 512 * 512) {
        int j = tid >> 9, k = tid & 511;
        BT4[tid] = f2bf(uW2[(size_t)k * 512 + j]);
        A_w[tid] = f2bf(uW1[(size_t)(512 + k) * 512 + j]);
        B_w[tid] = f2bf(mW2[tid]);
        BTx[(size_t)j * 1024 + k] = f2bf(uW1[(size_t)k * 512 + j]);
    }
    if (tid < 1024) bias1024[tid] = (tid < 512) ? mb1[tid] : 0.f;
}

// biasx[j] = ub1[j] + sum_l mb2[l] * uW1[512+l][j]   (one wave per j)
__global__ void prep_biasx(const float* __restrict__ ub1, const float* __restrict__ mb2,
                           const float* __restrict__ uW1, float* __restrict__ biasx)
{
    int wv = threadIdx.x >> 6, lane = threadIdx.x & 63;
    int j = blockIdx.x * 4 + wv;
    if (j >= 512) return;
    float s = 0.f;
    for (int l = lane; l < 512; l += 64)
        s += mb2[l] * uW1[(size_t)(512 + l) * 512 + j];
#pragma unroll
    for (int off = 32; off; off >>= 1) s += __shfl_xor(s, off, 64);
    if (lane == 0) biasx[j] = ub1[j] + s;
}

// Cast x (f32, M x 512) into cols [0,512) of XS (bf16, M x 1024)
__global__ void cast_x(const float* __restrict__ x, u16* __restrict__ XS, int total4)
{
    int i = blockIdx.x * 256 + threadIdx.x;
    if (i >= total4) return;
    int r = i >> 7, cg = i & 127;
    float4 v = ((const float4*)x)[i];
    us4 o = { f2bf(v.x), f2bf(v.y), f2bf(v.z), f2bf(v.w) };
    *(us4*)(XS + (size_t)r * 1024 + cg * 4) = o;
}

// ---------------------------------------------------------------------------
// 8-PHASE 256x256 GEMM (T3+T4+T5 faithful port): C[M,N] = A[M,K] @ BT[N][K].
// 8 waves (2M x 4N), wave owns 128x64, acc[8][4]. BK=64 split as 2 ks-halves.
// LDS: [buf][ks] 16KB regions for A and B (128 KB total, 1 block/CU).
// Per K-tile u (buf p=u&1), 4 phases; per phase: [vmcnt@ph0/ph2] -> barrier
// -> ds_read frags -> stage region freed by PREVIOUS phase's closing barrier
// (2 gload_lds) -> lgkm(0) -> setprio(1) 16 MFMA setprio(0) -> barrier.
// Rolling stage schedule: ph0->A-ks1(u+1), ph1->B-ks0(u+2), ph2->A-ks0(u+2),
// ph3->B-ks1(u+2). Load ledger (verified): prologue 14 loads + vmcnt(6);
// steady vmcnt(10) at ph0 completes R0,R1(u), at ph2 completes R2,R3(u);
// tail u=KT-1: vmcnt(4)/vmcnt(0). Counted vmcnt never drains mid-loop (T4).
// Swizzle: row-local chunk XOR within 64B rows (R9/R12-verified 0-conflict).
// ---------------------------------------------------------------------------
template<int OUTF32, int DOSILU, int DOBIAS, int DORES>
__global__ __launch_bounds__(512, 2)
void gemm_bt(const u16* __restrict__ Ag, int lda,
             const u16* __restrict__ Bg, int ldb,
             u16* __restrict__ Cb, float* __restrict__ Cf, int ldc,
             const float* __restrict__ bias,
             const u16* __restrict__ xres, const float* __restrict__ lat,
             const float* __restrict__ ub2v, int Nn, int M, int K)
{
    __shared__ __align__(16) u16 sA[2][2][256 * 32];   // [buf][ks] 16KB each
    __shared__ __align__(16) u16 sB[2][2][256 * 32];

    // T1: XCD-chunked bijective remap (m204)
    const int gx  = gridDim.x;
    const int nwg = gx * (int)gridDim.y;
    int flat = blockIdx.y * gx + blockIdx.x;
    {
        int q = nwg >> 3, r = nwg & 7;
        int xcd = flat & 7, jj = flat >> 3;
        flat = (xcd < r ? xcd * (q + 1) : r * (q + 1) + (xcd - r) * q) + jj;
    }
    const int m0 = (flat / gx) * 256;
    const int n0 = (flat % gx) * 256;

    const int tid  = threadIdx.x;
    const int wid  = tid >> 6;          // 0..7
    const int lane = tid & 63;
    const int lr   = lane & 15;
    const int h    = lane >> 4;
    const int wr   = wid >> 2;          // 0..1  M half (128 rows)
    const int wc   = wid & 3;           // 0..3  N quarter (64 cols)
    const int hs   = (h ^ ((lr >> 1) & 3)) * 8;   // swizzled read offset

    f32x4 acc[8][4];
#pragma unroll
    for (int i = 0; i < 8; ++i)
#pragma unroll
        for (int j = 0; j < 4; ++j)
            acc[i][j] = (f32x4){0.f, 0.f, 0.f, 0.f};

    const int KT = K >> 6;              // K-tiles of 64 (8 or 16 here)

    // Stage one 16KB region (256 rows x 32 cols bf16): 2 loads/thread.
    // Linear LDS dest q*16B; source chunk = (q&3) ^ ((row>>1)&3) (row-local).
    auto stageR = [&](bool isA, int ks, int tile) {
        if (tile >= KT) return;
        const int pp = tile & 1;
        const int k0 = (tile << 6) + (ks << 5);
#pragma unroll
        for (int l = 0; l < 2; ++l) {
            int q = l * 512 + tid;
            int row = q >> 2;
            int csrc = ((q & 3) ^ ((row >> 1) & 3)) * 8;
            if (isA) {
                int grow = m0 + row; grow = grow < M ? grow : M - 1;
                gload_lds16(Ag + (size_t)grow * lda + k0 + csrc,
                            &sA[pp][ks][q * 8]);
            } else {
                gload_lds16(Bg + (size_t)(n0 + row) * ldb + k0 + csrc,
                            &sB[pp][ks][q * 8]);
            }
        }
    };

    // Prologue: R0(0),R1(0),R2(0),R3(0), R0(1),R1(1),R2(1)  = 14 loads.
    stageR(false, 0, 0);   // B-ks0(0)
    stageR(true,  0, 0);   // A-ks0(0)
    stageR(false, 1, 0);   // B-ks1(0)
    stageR(true,  1, 0);   // A-ks1(0)
    stageR(false, 0, 1);   // B-ks0(1)
    stageR(true,  0, 1);   // A-ks0(1)
    stageR(false, 1, 1);   // B-ks1(1)
    asm volatile("s_waitcnt vmcnt(6)" ::: "memory");   // tile0 landed
    __builtin_amdgcn_sched_barrier(0);
    __builtin_amdgcn_s_barrier();

    for (int u = 0; u < KT; ++u) {
        const int p = u & 1;
        bf16x8 bfr[4], af[4];

        // ---- ph0: ks0, acc rows 0-3 ----
        if (u == KT - 1) { asm volatile("s_waitcnt vmcnt(4)" ::: "memory"); }
        else             { asm volatile("s_waitcnt vmcnt(10)" ::: "memory"); }
        __builtin_amdgcn_sched_barrier(0);
        __builtin_amdgcn_s_barrier();          // all threads' R0,R1(u) landed
#pragma unroll
        for (int j = 0; j < 4; ++j)
            bfr[j] = *(const bf16x8*)&sB[p][0][(wc * 64 + j * 16 + lr) * 32 + hs];
#pragma unroll
        for (int i = 0; i < 4; ++i)
            af[i] = *(const bf16x8*)&sA[p][0][(wr * 128 + i * 16 + lr) * 32 + hs];
        stageR(true, 1, u + 1);                // A-ks1(u+1): freed by (u-1)ph3
        asm volatile("s_waitcnt lgkmcnt(0)" ::: "memory");
        __builtin_amdgcn_sched_barrier(0);
        __builtin_amdgcn_s_setprio(1);
#pragma unroll
        for (int i = 0; i < 4; ++i)
#pragma unroll
            for (int j = 0; j < 4; ++j)
                acc[i][j] = __builtin_amdgcn_mfma_f32_16x16x32_bf16(af[i], bfr[j], acc[i][j], 0, 0, 0);
        __builtin_amdgcn_s_setprio(0);
        __builtin_amdgcn_s_barrier();          // close ph0 (B-ks0(p) freed)

        // ---- ph1: ks0, acc rows 4-7 ----
#pragma unroll
        for (int i = 0; i < 4; ++i)
            af[i] = *(const bf16x8*)&sA[p][0][(wr * 128 + (i + 4) * 16 + lr) * 32 + hs];
        stageR(false, 0, u + 2);               // B-ks0(u+2) into freed region
        asm volatile("s_waitcnt lgkmcnt(0)" ::: "memory");
        __builtin_amdgcn_sched_barrier(0);
        __builtin_amdgcn_s_setprio(1);
#pragma unroll
        for (int i = 0; i < 4; ++i)
#pragma unroll
            for (int j = 0; j < 4; ++j)
                acc[i + 4][j] = __builtin_amdgcn_mfma_f32_16x16x32_bf16(af[i], bfr[j], acc[i + 4][j], 0, 0, 0);
        __builtin_amdgcn_s_setprio(0);
        __builtin_amdgcn_s_barrier();          // close ph1 (A-ks0(p) freed)

        // ---- ph2: ks1, acc rows 0-3 ----
        if (u == KT - 1) { asm volatile("s_waitcnt vmcnt(0)" ::: "memory"); }
        else             { asm volatile("s_waitcnt vmcnt(10)" ::: "memory"); }
        __builtin_amdgcn_sched_barrier(0);
        __builtin_amdgcn_s_barrier();          // all threads' R2,R3(u) landed
#pragma unroll
        for (int j = 0; j < 4; ++j)
            bfr[j] = *(const bf16x8*)&sB[p][1][(wc * 64 + j * 16 + lr) * 32 + hs];
#pragma unroll
        for (int i = 0; i < 4; ++i)
            af[i] = *(const bf16x8*)&sA[p][1][(wr * 128 + i * 16 + lr) * 32 + hs];
        stageR(true, 0, u + 2);                // A-ks0(u+2) into freed region
        asm volatile("s_waitcnt lgkmcnt(0)" ::: "memory");
        __builtin_amdgcn_sched_barrier(0);
        __builtin_amdgcn_s_setprio(1);
#pragma unroll
        for (int i = 0; i < 4; ++i)
#pragma unroll
            for (int j = 0; j < 4; ++j)
                acc[i][j] = __builtin_amdgcn_mfma_f32_16x16x32_bf16(af[i], bfr[j], acc[i][j], 0, 0, 0);
        __builtin_amdgcn_s_setprio(0);
        __builtin_amdgcn_s_barrier();          // close ph2 (B-ks1(p) freed)

        // ---- ph3: ks1, acc rows 4-7 ----
#pragma unroll
        for (int i = 0; i < 4; ++i)
            af[i] = *(const bf16x8*)&sA[p][1][(wr * 128 + (i + 4) * 16 + lr) * 32 + hs];
        stageR(false, 1, u + 2);               // B-ks1(u+2) into freed region
        asm volatile("s_waitcnt lgkmcnt(0)" ::: "memory");
        __builtin_amdgcn_sched_barrier(0);
        __builtin_amdgcn_s_setprio(1);
#pragma unroll
        for (int i = 0; i < 4; ++i)
#pragma unroll
            for (int j = 0; j < 4; ++j)
                acc[i + 4][j] = __builtin_amdgcn_mfma_f32_16x16x32_bf16(af[i], bfr[j], acc[i + 4][j], 0, 0, 0);
        __builtin_amdgcn_s_setprio(0);
        __builtin_amdgcn_s_barrier();          // close ph3 (A-ks1(p) freed)
    }

    float bb[4];
#pragma unroll
    for (int j = 0; j < 4; ++j)
        bb[j] = DOBIAS ? bias[n0 + wc * 64 + j * 16 + lr] : 0.f;

    // D layout (m89-verified): col = lane&15, row = 4*(lane>>4) + reg
#pragma unroll
    for (int i = 0; i < 8; ++i) {
#pragma unroll
        for (int rj = 0; rj < 4; ++rj) {
            int grow = m0 + wr * 128 + i * 16 + 4 * h + rj;
            if (grow >= M) continue;
            size_t ro = (size_t)grow * ldc;
            size_t xo = 0, lo = 0;
            if (DORES) {
                int nn = grow % Nn;
                xo = (size_t)grow * 1024;      // XS row (bf16 x in cols 0..511)
                lo = (size_t)nn * 512;
            }
#pragma unroll
            for (int j = 0; j < 4; ++j) {
                int gcol = n0 + wc * 64 + j * 16 + lr;
                float v = acc[i][j][rj] + bb[j];
                if (DOSILU) v = v * __builtin_amdgcn_rcpf(1.f + __expf(-v));
                if (DORES)
                    v += bf2f(xres[xo + gcol]) + lat[lo + gcol] + ub2v[gcol];
                if (OUTF32) Cf[ro + gcol] = v;
                else        Cb[ro + gcol] = f2bf(v);
            }
        }
    }
}

// ---------------------------------------------------------------------------
// S[row] = (1/8) * sum_k silu(c_projb[row] + n_proj[b, knn[n,k]])
// (mb1 folded into c_proj via G1 bias.)  Writes cols 512.. of XS.
// ---------------------------------------------------------------------------
__global__ void gather_silu_mean(const u16* __restrict__ P, const int* __restrict__ knn,
                                 u16* __restrict__ XS, int Nn, int M)
{
    int wid = threadIdx.x >> 6, lane = threadIdx.x & 63;
    int row = blockIdx.x * 4 + wid;
    if (row >= M) return;
    int b = row / Nn, n = row - b * Nn;
    int c0 = lane * 8;

    int idx[8];
#pragma unroll
    for (int k = 0; k < 8; ++k) idx[k] = knn[n * 8 + k];

    us8 cu = *(const us8*)(P + (size_t)row * 1024 + c0);
    const u16* Pn = P + (size_t)b * Nn * 1024 + 512 + c0;
    us8 nb[8];
#pragma unroll
    for (int k = 0; k < 8; ++k) nb[k] = *(const us8*)(Pn + (size_t)idx[k] * 1024);

    float base[8], accv[8];
#pragma unroll
    for (int i = 0; i < 8; ++i) { base[i] = bf2f(cu[i]); accv[i] = 0.f; }

#pragma unroll
    for (int k = 0; k < 8; ++k)
#pragma unroll
        for (int i = 0; i < 8; ++i) {
            float pv = base[i] + bf2f(nb[k][i]);
            accv[i] += pv * __builtin_amdgcn_rcpf(1.f + __expf(-pv));
        }

    us8 o;
#pragma unroll
    for (int i = 0; i < 8; ++i) o[i] = f2bf(accv[i] * 0.125f);
    *(us8*)(XS + (size_t)row * 1024 + 512 + c0) = o;
}

// ---------------------------------------------------------------------------
// LN: reads bf16 pre-LN rows (Yt), writes f32 output Y.
// ---------------------------------------------------------------------------
__global__ void ln_fuse(const u16* __restrict__ Yt, float* __restrict__ Y,
                        const float* __restrict__ g, const float* __restrict__ bta,
                        int M)
{
    int wid = threadIdx.x >> 6, lane = threadIdx.x & 63;
    int row = blockIdx.x * 4 + wid;
    if (row >= M) return;
    int c0 = lane * 8;

    us8 u = *(const us8*)(Yt + (size_t)row * 512 + c0);
    float v[8];
#pragma unroll
    for (int i = 0; i < 8; ++i) v[i] = bf2f(u[i]);

    float s = 0.f;
#pragma unroll
    for (int i = 0; i < 8; ++i) s += v[i];
#pragma unroll
    for (int off = 32; off > 0; off >>= 1) s += __shfl_xor(s, off, 64);
    float mu = s * (1.f / 512.f);

    float q = 0.f;
#pragma unroll
    for (int i = 0; i < 8; ++i) { float d = v[i] - mu; q += d * d; }
#pragma unroll
    for (int off = 32; off > 0; off >>= 1) q += __shfl_xor(q, off, 64);
    float inv = rsqrtf(q * (1.f / 512.f) + 1e-5f);

    float* yr = Y + (size_t)row * 512 + c0;
#pragma unroll
    for (int i = 0; i < 8; ++i) yr[i] = (v[i] - mu) * inv * g[c0 + i] + bta[c0 + i];
}

extern "C" void kernel_launch(void* const* d_in, const int* in_sizes, int n_in,
                              void* d_out, int out_size, void* d_ws, size_t ws_size,
                              hipStream_t stream)
{
    const float* x   = (const float*)d_in[0];
    const float* lat = (const float*)d_in[1];
    const int*   knn = (const int*)d_in[2];
    const float* mW1 = (const float*)d_in[3];
    const float* mb1 = (const float*)d_in[4];
    const float* mW2 = (const float*)d_in[5];
    const float* mb2 = (const float*)d_in[6];
    const float* uW1 = (const float*)d_in[7];
    const float* ub1 = (const float*)d_in[8];
    const float* uW2 = (const float*)d_in[9];
    const float* ub2 = (const float*)d_in[10];
    const float* lng = (const float*)d_in[11];
    const float* lnb = (const float*)d_in[12];

    const int Nn = 10242;
    const int M  = 4 * Nn;       // 40968

    char* ws = (char*)d_ws;
    u16* BT1 = (u16*)ws; ws += (size_t)1024 * 512 * 2;
    u16* BTx = (u16*)ws; ws += (size_t)512 * 1024 * 2;
    u16* BT4 = (u16*)ws; ws += (size_t)512 * 512 * 2;
    u16* A_w = (u16*)ws; ws += (size_t)512 * 512 * 2;
    u16* B_w = (u16*)ws; ws += (size_t)512 * 512 * 2;
    float* bias1024 = (float*)ws; ws += 1024 * 4;
    float* biasx    = (float*)ws; ws += 512 * 4;
    u16* XS = (u16*)ws; ws += (size_t)M * 1024 * 2;    // [x_bf16 | S]
    u16* P  = (u16*)ws; ws += (size_t)M * 1024 * 2;    // [c_proj+mb1 | n_proj]
    u16* T  = (u16*)ws; ws += (size_t)M * 512 * 2;     // silu(u-pre)
    u16* Yt = P;                    // P dead after gather; reuse for pre-LN
    float* Y = (float*)d_out;

    const int MB = (M + 255) / 256;  // 161

    prep_weights<<<2048, 256, 0, stream>>>(mW1, mW2, uW1, uW2, mb1,
                                           BT1, BT4, A_w, B_w, BTx, bias1024);
    prep_biasx<<<128, 256, 0, stream>>>(ub1, mb2, uW1, biasx);
    cast_x<<<(M * 512 / 4 + 255) / 256, 256, 0, stream>>>(x, XS, M * 512 / 4);

    // Wc^T -> BTx cols 512..1023  (M=512, N=512, K=512)
    gemm_bt<0, 0, 0, 0><<<dim3(2, 2), 512, 0, stream>>>(
        A_w, 512, B_w, 512, BTx + 512, nullptr, 1024,
        nullptr, nullptr, nullptr, nullptr, 0, 512, 512);

    // G1: P = x @ [mW1_top | mW1_bot] + [mb1 | 0]   (M x 1024, K=512)
    gemm_bt<0, 0, 1, 0><<<dim3(4, MB), 512, 0, stream>>>(
        XS, 1024, BT1, 512, P, nullptr, 1024,
        bias1024, nullptr, nullptr, nullptr, 0, M, 512);

    gather_silu_mean<<<(M + 3) / 4, 256, 0, stream>>>(P, knn, XS, Nn, M);

    // Gx: T = silu([x|S] @ [uW1_top; Wc] + biasx)   (M x 512, K=1024)
    gemm_bt<0, 1, 1, 0><<<dim3(2, MB), 512, 0, stream>>>(
        XS, 1024, BTx, 1024, T, nullptr, 512,
        biasx, nullptr, nullptr, nullptr, 0, M, 1024);

    // G4: Yt = bf16(T @ uW2 + x + lat + ub2)   (pre-LN, bf16 into P's buffer)
    gemm_bt<0, 0, 0, 1><<<dim3(2, MB), 512, 0, stream>>>(
        T, 512, BT4, 512, Yt, nullptr, 512,
        nullptr, XS, lat, ub2, Nn, M, 512);

    ln_fuse<<<(M + 3) / 4, 256, 0, stream>>>(Yt, Y, lng, lnb, M);
}

// Round 15
// 305.553 us; speedup vs baseline: 1.1700x; 1.1352x over previous
//
#include <hip/hip_runtime.h>
#include <hip/hip_bf16.h>
#include <cstdint>

typedef unsigned short u16;
typedef __attribute__((ext_vector_type(8))) __bf16 bf16x8;
typedef __attribute__((ext_vector_type(4))) float f32x4;
typedef __attribute__((ext_vector_type(8))) u16 us8;
typedef __attribute__((ext_vector_type(4))) u16 us4;

__device__ __forceinline__ float bf2f(u16 u) {
    return __uint_as_float(((unsigned int)u) << 16);
}
__device__ __forceinline__ u16 f2bf(float f) {
    unsigned int u = __float_as_uint(f);
    unsigned int r = (u + 0x7fffu + ((u >> 16) & 1u)) >> 16;
    return (u16)r;
}

__device__ __forceinline__ void gload_lds16(const void* src, void* dst) {
    __builtin_amdgcn_global_load_lds(
        (const __attribute__((address_space(1))) void*)src,
        (__attribute__((address_space(3))) void*)dst,
        16, 0, 0);
}

// ---------------------------------------------------------------------------
// Weight prep v2: LDS-tiled transpose+cast (coalesced reads AND writes; the
// R11 version read f32 at stride 2KB = ~16x overfetch). Five 512x512
// transposes selected by blockIdx.z:
//  z=0: mW1[0:512,:]^T    -> BT1 rows 0-511   (ld 512)
//  z=1: mW1[512:1024,:]^T -> BT1 rows 512-1023(ld 512)
//  z=2: uW2^T             -> BT4              (ld 512)
//  z=3: uW1[512:1024,:]^T -> A_w              (ld 512)
//  z=4: uW1[0:512,:]^T    -> BTx cols 0-511   (ld 1024)
// ---------------------------------------------------------------------------
__global__ void prep_transpose(const float* __restrict__ mW1,
                               const float* __restrict__ uW2,
                               const float* __restrict__ uW1,
                               u16* __restrict__ BT1, u16* __restrict__ BT4,
                               u16* __restrict__ A_w, u16* __restrict__ BTx)
{
    __shared__ float tile[32][33];
    const float* src; u16* dst; int dld;
    switch (blockIdx.z) {
        case 0: src = mW1;                  dst = BT1;                  dld = 512;  break;
        case 1: src = mW1 + 512 * 512;      dst = BT1 + 512 * 512;      dld = 512;  break;
        case 2: src = uW2;                  dst = BT4;                  dld = 512;  break;
        case 3: src = uW1 + 512 * 512;      dst = A_w;                  dld = 512;  break;
        default: src = uW1;                 dst = BTx;                  dld = 1024; break;
    }
    int tx = threadIdx.x & 31, ty = threadIdx.x >> 5;      // 32 x 8
    int x0 = blockIdx.x * 32, y0 = blockIdx.y * 32;
#pragma unroll
    for (int i = 0; i < 4; ++i)
        tile[ty + 8 * i][tx] = src[(size_t)(y0 + ty + 8 * i) * 512 + x0 + tx];
    __syncthreads();
#pragma unroll
    for (int i = 0; i < 4; ++i)
        dst[(size_t)(x0 + ty + 8 * i) * dld + y0 + tx] = f2bf(tile[tx][ty + 8 * i]);
}

// B_w = bf16(mW2) (coalesced copy, float4->us4) ; bias1024 = [mb1 | 0]
__global__ void prep_misc(const float* __restrict__ mW2, const float* __restrict__ mb1,
                          u16* __restrict__ B_w, float* __restrict__ bias1024)
{
    int i = blockIdx.x * 256 + threadIdx.x;            // [0, 65536)
    float4 v = ((const float4*)mW2)[i];
    us4 o = { f2bf(v.x), f2bf(v.y), f2bf(v.z), f2bf(v.w) };
    *(us4*)(B_w + (size_t)i * 4) = o;
    if (i < 1024) bias1024[i] = (i < 512) ? mb1[i] : 0.f;
}

// biasx[j] = ub1[j] + sum_l mb2[l] * uW1[512+l][j]   (one wave per j)
__global__ void prep_biasx(const float* __restrict__ ub1, const float* __restrict__ mb2,
                           const float* __restrict__ uW1, float* __restrict__ biasx)
{
    int wv = threadIdx.x >> 6, lane = threadIdx.x & 63;
    int j = blockIdx.x * 4 + wv;
    if (j >= 512) return;
    float s = 0.f;
    for (int l = lane; l < 512; l += 64)
        s += mb2[l] * uW1[(size_t)(512 + l) * 512 + j];
#pragma unroll
    for (int off = 32; off; off >>= 1) s += __shfl_xor(s, off, 64);
    if (lane == 0) biasx[j] = ub1[j] + s;
}

// Cast x (f32, M x 512) into cols [0,512) of XS (bf16, M x 1024)
__global__ void cast_x(const float* __restrict__ x, u16* __restrict__ XS, int total4)
{
    int i = blockIdx.x * 256 + threadIdx.x;
    if (i >= total4) return;
    int r = i >> 7, cg = i & 127;
    float4 v = ((const float4*)x)[i];
    us4 o = { f2bf(v.x), f2bf(v.y), f2bf(v.z), f2bf(v.w) };
    *(us4*)(XS + (size_t)r * 1024 + cg * 4) = o;
}

// ---------------------------------------------------------------------------
// GEMM: C[M,N] = A[M,K] (bf16, lda) @ BT[N][K] (bf16, ldb)
// R11 best-known-good (309 us total): triple-buffered LDS [128][32], depth-2
// prefetch, counted vmcnt(4), SINGLE barrier per K-step, row-local XOR
// swizzle (0 conflicts, coalescing intact). Byte-identical to the 309 run.
// ---------------------------------------------------------------------------
template<int OUTF32, int DOSILU, int DOBIAS, int DORES>
__global__ __launch_bounds__(256, 3)
void gemm_bt(const u16* __restrict__ A, int lda,
             const u16* __restrict__ Bt, int ldb,
             u16* __restrict__ Cb, float* __restrict__ Cf, int ldc,
             const float* __restrict__ bias,
             const u16* __restrict__ xres, const float* __restrict__ lat,
             const float* __restrict__ ub2v, int Nn, int M, int K)
{
    __shared__ __align__(16) u16 lA[3][128 * 32];   // 3 x 8 KB
    __shared__ __align__(16) u16 lB[3][128 * 32];   // 3 x 8 KB

    // T1: XCD-chunked bijective remap (m204)
    const int gx  = gridDim.x;
    const int nwg = gx * (int)gridDim.y;
    int flat = blockIdx.y * gx + blockIdx.x;
    {
        int q = nwg >> 3, r = nwg & 7;
        int xcd = flat & 7, jj = flat >> 3;
        flat = (xcd < r ? xcd * (q + 1) : r * (q + 1) + (xcd - r) * q) + jj;
    }
    const int m0 = (flat / gx) * 128;
    const int n0 = (flat % gx) * 128;

    const int tid  = threadIdx.x;
    const int wid  = tid >> 6;
    const int lane = tid & 63;
    const int lr   = lane & 15;
    const int h    = lane >> 4;
    const int wm   = (wid >> 1) * 64;
    const int wn   = (wid & 1) * 64;
    const int sw   = (lr >> 1) & 3;     // read-side swizzle (= (row>>1)&3)
    const int hs   = (h ^ sw) * 8;      // swizzled chunk offset (u16 units)

    f32x4 acc[4][4];
#pragma unroll
    for (int i = 0; i < 4; ++i)
#pragma unroll
        for (int j = 0; j < 4; ++j)
            acc[i][j] = (f32x4){0.f, 0.f, 0.f, 0.f};

    const int NT = K >> 5;

    const int csrc = ((lane & 3) ^ ((lane >> 3) & 3)) * 8;  // u16 offset in row

    auto stageA = [&](int t, int buf) {
#pragma unroll
        for (int q = 0; q < 2; ++q) {
            int gc = (wid * 2 + q) * 64 + lane;
            int r = gc >> 2;
            int grow = m0 + r; grow = grow < M ? grow : M - 1;
            const u16* src = A + (size_t)grow * lda + (t << 5) + csrc;
            gload_lds16(src, &lA[buf][(wid * 2 + q) * 512]);
        }
    };
    auto stageB = [&](int t, int buf) {
#pragma unroll
        for (int q = 0; q < 2; ++q) {
            int gc = (wid * 2 + q) * 64 + lane;
            int r = gc >> 2;
            const u16* src = Bt + (size_t)(n0 + r) * ldb + (t << 5) + csrc;
            gload_lds16(src, &lB[buf][(wid * 2 + q) * 512]);
        }
    };

    // prologue: tiles 0 and 1 in flight (8 outstanding VMEM/thread)
    stageA(0, 0); stageB(0, 0);
    stageA(1, 1); stageB(1, 1);

    for (int t = 0; t < NT; ++t) {
        const int buf = t % 3;
        if (t + 1 < NT) {
            asm volatile("s_waitcnt vmcnt(4)" ::: "memory");
        } else {
            asm volatile("s_waitcnt vmcnt(0)" ::: "memory");
        }
        __builtin_amdgcn_sched_barrier(0);
        __builtin_amdgcn_s_barrier();         // tile t visible; (t-1)%3 free
        __builtin_amdgcn_sched_barrier(0);

        if (t + 2 < NT) {
            stageA(t + 2, (t + 2) % 3);
            stageB(t + 2, (t + 2) % 3);
        }

        bf16x8 af[4], bfr[4];
#pragma unroll
        for (int i = 0; i < 4; ++i) {
            af[i]  = *(const bf16x8*)&lA[buf][(wm + i * 16 + lr) * 32 + hs];
            bfr[i] = *(const bf16x8*)&lB[buf][(wn + i * 16 + lr) * 32 + hs];
        }
#pragma unroll
        for (int i = 0; i < 4; ++i)
#pragma unroll
            for (int j = 0; j < 4; ++j)
                acc[i][j] = __builtin_amdgcn_mfma_f32_16x16x32_bf16(af[i], bfr[j], acc[i][j], 0, 0, 0);
        // no 2nd barrier: ds_reads retire before next step's barrier via the
        // compiler's lgkmcnt-before-MFMA; buffer reuse is 3 steps away.
    }

    float bv[4] = {0.f, 0.f, 0.f, 0.f};
    if (DOBIAS) {
#pragma unroll
        for (int j = 0; j < 4; ++j) bv[j] = bias[n0 + wn + j * 16 + lr];
    }
    // D layout (m89-verified): col = lane&15, row = 4*(lane>>4) + reg
#pragma unroll
    for (int i = 0; i < 4; ++i) {
#pragma unroll
        for (int rj = 0; rj < 4; ++rj) {
            int grow = m0 + wm + i * 16 + 4 * h + rj;
            if (grow >= M) continue;
            size_t ro = (size_t)grow * ldc;
            size_t xo = 0, lo = 0;
            if (DORES) {
                int nn = grow % Nn;
                xo = (size_t)grow * 1024;      // XS row (bf16 x in cols 0..511)
                lo = (size_t)nn * 512;
            }
#pragma unroll
            for (int j = 0; j < 4; ++j) {
                int gcol = n0 + wn + j * 16 + lr;
                float v = acc[i][j][rj] + bv[j];
                if (DOSILU) v = v * __builtin_amdgcn_rcpf(1.f + __expf(-v));
                if (DORES)
                    v += bf2f(xres[xo + gcol]) + lat[lo + gcol] + ub2v[gcol];
                if (OUTF32) Cf[ro + gcol] = v;
                else        Cb[ro + gcol] = f2bf(v);
            }
        }
    }
}

// ---------------------------------------------------------------------------
// S[row] = (1/8) * sum_k silu(c_projb[row] + n_proj[b, knn[n,k]])
// (mb1 folded into c_proj via G1 bias.)  Writes cols 512.. of XS.
// ---------------------------------------------------------------------------
__global__ void gather_silu_mean(const u16* __restrict__ P, const int* __restrict__ knn,
                                 u16* __restrict__ XS, int Nn, int M)
{
    int wid = threadIdx.x >> 6, lane = threadIdx.x & 63;
    int row = blockIdx.x * 4 + wid;
    if (row >= M) return;
    int b = row / Nn, n = row - b * Nn;
    int c0 = lane * 8;

    int idx[8];
#pragma unroll
    for (int k = 0; k < 8; ++k) idx[k] = knn[n * 8 + k];

    us8 cu = *(const us8*)(P + (size_t)row * 1024 + c0);
    const u16* Pn = P + (size_t)b * Nn * 1024 + 512 + c0;
    us8 nb[8];
#pragma unroll
    for (int k = 0; k < 8; ++k) nb[k] = *(const us8*)(Pn + (size_t)idx[k] * 1024);

    float base[8], accv[8];
#pragma unroll
    for (int i = 0; i < 8; ++i) { base[i] = bf2f(cu[i]); accv[i] = 0.f; }

#pragma unroll
    for (int k = 0; k < 8; ++k)
#pragma unroll
        for (int i = 0; i < 8; ++i) {
            float pv = base[i] + bf2f(nb[k][i]);
            accv[i] += pv * __builtin_amdgcn_rcpf(1.f + __expf(-pv));
        }

    us8 o;
#pragma unroll
    for (int i = 0; i < 8; ++i) o[i] = f2bf(accv[i] * 0.125f);
    *(us8*)(XS + (size_t)row * 1024 + 512 + c0) = o;
}

// ---------------------------------------------------------------------------
// LN: reads bf16 pre-LN rows (Yt), writes f32 output Y.
// ---------------------------------------------------------------------------
__global__ void ln_fuse(const u16* __restrict__ Yt, float* __restrict__ Y,
                        const float* __restrict__ g, const float* __restrict__ bta,
                        int M)
{
    int wid = threadIdx.x >> 6, lane = threadIdx.x & 63;
    int row = blockIdx.x * 4 + wid;
    if (row >= M) return;
    int c0 = lane * 8;

    us8 u = *(const us8*)(Yt + (size_t)row * 512 + c0);
    float v[8];
#pragma unroll
    for (int i = 0; i < 8; ++i) v[i] = bf2f(u[i]);

    float s = 0.f;
#pragma unroll
    for (int i = 0; i < 8; ++i) s += v[i];
#pragma unroll
    for (int off = 32; off > 0; off >>= 1) s += __shfl_xor(s, off, 64);
    float mu = s * (1.f / 512.f);

    float q = 0.f;
#pragma unroll
    for (int i = 0; i < 8; ++i) { float d = v[i] - mu; q += d * d; }
#pragma unroll
    for (int off = 32; off > 0; off >>= 1) q += __shfl_xor(q, off, 64);
    float inv = rsqrtf(q * (1.f / 512.f) + 1e-5f);

    float* yr = Y + (size_t)row * 512 + c0;
#pragma unroll
    for (int i = 0; i < 8; ++i) yr[i] = (v[i] - mu) * inv * g[c0 + i] + bta[c0 + i];
}

extern "C" void kernel_launch(void* const* d_in, const int* in_sizes, int n_in,
                              void* d_out, int out_size, void* d_ws, size_t ws_size,
                              hipStream_t stream)
{
    const float* x   = (const float*)d_in[0];
    const float* lat = (const float*)d_in[1];
    const int*   knn = (const int*)d_in[2];
    const float* mW1 = (const float*)d_in[3];
    const float* mb1 = (const float*)d_in[4];
    const float* mW2 = (const float*)d_in[5];
    const float* mb2 = (const float*)d_in[6];
    const float* uW1 = (const float*)d_in[7];
    const float* ub1 = (const float*)d_in[8];
    const float* uW2 = (const float*)d_in[9];
    const float* ub2 = (const float*)d_in[10];
    const float* lng = (const float*)d_in[11];
    const float* lnb = (const float*)d_in[12];

    const int Nn = 10242;
    const int M  = 4 * Nn;       // 40968

    char* ws = (char*)d_ws;
    u16* BT1 = (u16*)ws; ws += (size_t)1024 * 512 * 2;
    u16* BTx = (u16*)ws; ws += (size_t)512 * 1024 * 2;
    u16* BT4 = (u16*)ws; ws += (size_t)512 * 512 * 2;
    u16* A_w = (u16*)ws; ws += (size_t)512 * 512 * 2;
    u16* B_w = (u16*)ws; ws += (size_t)512 * 512 * 2;
    float* bias1024 = (float*)ws; ws += 1024 * 4;
    float* biasx    = (float*)ws; ws += 512 * 4;
    u16* XS = (u16*)ws; ws += (size_t)M * 1024 * 2;    // [x_bf16 | S]
    u16* P  = (u16*)ws; ws += (size_t)M * 1024 * 2;    // [c_proj+mb1 | n_proj]
    u16* T  = (u16*)ws; ws += (size_t)M * 512 * 2;     // silu(u-pre)
    u16* Yt = P;                    // P dead after gather; reuse for pre-LN
    float* Y = (float*)d_out;

    const int MB = (M + 127) / 128;  // 321

    prep_transpose<<<dim3(16, 16, 5), 256, 0, stream>>>(mW1, uW2, uW1,
                                                        BT1, BT4, A_w, BTx);
    prep_misc<<<256, 256, 0, stream>>>(mW2, mb1, B_w, bias1024);
    prep_biasx<<<128, 256, 0, stream>>>(ub1, mb2, uW1, biasx);
    cast_x<<<(M * 512 / 4 + 255) / 256, 256, 0, stream>>>(x, XS, M * 512 / 4);

    // Wc^T -> BTx cols 512..1023  (M=512, N=512, K=512)
    gemm_bt<0, 0, 0, 0><<<dim3(4, 4), 256, 0, stream>>>(
        A_w, 512, B_w, 512, BTx + 512, nullptr, 1024,
        nullptr, nullptr, nullptr, nullptr, 0, 512, 512);

    // G1: P = x @ [mW1_top | mW1_bot] + [mb1 | 0]   (M x 1024, K=512)
    gemm_bt<0, 0, 1, 0><<<dim3(8, MB), 256, 0, stream>>>(
        XS, 1024, BT1, 512, P, nullptr, 1024,
        bias1024, nullptr, nullptr, nullptr, 0, M, 512);

    gather_silu_mean<<<(M + 3) / 4, 256, 0, stream>>>(P, knn, XS, Nn, M);

    // Gx: T = silu([x|S] @ [uW1_top; Wc] + biasx)   (M x 512, K=1024)
    gemm_bt<0, 1, 1, 0><<<dim3(4, MB), 256, 0, stream>>>(
        XS, 1024, BTx, 1024, T, nullptr, 512,
        biasx, nullptr, nullptr, nullptr, 0, M, 1024);

    // G4: Yt = bf16(T @ uW2 + x + lat + ub2)   (pre-LN, bf16 into P's buffer)
    gemm_bt<0, 0, 0, 1><<<dim3(4, MB), 256, 0, stream>>>(
        T, 512, BT4, 512, Yt, nullptr, 512,
        nullptr, XS, lat, ub2, Nn, M, 512);

    ln_fuse<<<(M + 3) / 4, 256, 0, stream>>>(Yt, Y, lng, lnb, M);
}

// Round 17
// 288.224 us; speedup vs baseline: 1.2403x; 1.0601x over previous
//
#include <hip/hip_runtime.h>
#include <hip/hip_bf16.h>
#include <cstdint>

typedef unsigned short u16;
typedef __attribute__((ext_vector_type(8))) __bf16 bf16x8;
typedef __attribute__((ext_vector_type(4))) float f32x4;
typedef __attribute__((ext_vector_type(8))) u16 us8;
typedef __attribute__((ext_vector_type(4))) u16 us4;

__device__ __forceinline__ float bf2f(u16 u) {
    return __uint_as_float(((unsigned int)u) << 16);
}
__device__ __forceinline__ u16 f2bf(float f) {
    unsigned int u = __float_as_uint(f);
    unsigned int r = (u + 0x7fffu + ((u >> 16) & 1u)) >> 16;
    return (u16)r;
}

__device__ __forceinline__ void gload_lds16(const void* src, void* dst) {
    __builtin_amdgcn_global_load_lds(
        (const __attribute__((address_space(1))) void*)src,
        (__attribute__((address_space(3))) void*)dst,
        16, 0, 0);
}

// ---------------------------------------------------------------------------
// Weight prep: LDS-tiled transpose+cast (coalesced both sides, R15-verified).
//  z=0: mW1[0:512,:]^T    -> BT1 rows 0-511   (ld 512)
//  z=1: mW1[512:1024,:]^T -> BT1 rows 512-1023(ld 512)
//  z=2: uW2^T             -> BT4              (ld 512)
//  z=3: uW1[512:1024,:]^T -> A_w              (ld 512)
//  z=4: uW1[0:512,:]^T    -> BTx cols 0-511   (ld 1024)
// ---------------------------------------------------------------------------
__global__ void prep_transpose(const float* __restrict__ mW1,
                               const float* __restrict__ uW2,
                               const float* __restrict__ uW1,
                               u16* __restrict__ BT1, u16* __restrict__ BT4,
                               u16* __restrict__ A_w, u16* __restrict__ BTx)
{
    __shared__ float tile[32][33];
    const float* src; u16* dst; int dld;
    switch (blockIdx.z) {
        case 0: src = mW1;                  dst = BT1;                  dld = 512;  break;
        case 1: src = mW1 + 512 * 512;      dst = BT1 + 512 * 512;      dld = 512;  break;
        case 2: src = uW2;                  dst = BT4;                  dld = 512;  break;
        case 3: src = uW1 + 512 * 512;      dst = A_w;                  dld = 512;  break;
        default: src = uW1;                 dst = BTx;                  dld = 1024; break;
    }
    int tx = threadIdx.x & 31, ty = threadIdx.x >> 5;      // 32 x 8
    int x0 = blockIdx.x * 32, y0 = blockIdx.y * 32;
#pragma unroll
    for (int i = 0; i < 4; ++i)
        tile[ty + 8 * i][tx] = src[(size_t)(y0 + ty + 8 * i) * 512 + x0 + tx];
    __syncthreads();
#pragma unroll
    for (int i = 0; i < 4; ++i)
        dst[(size_t)(x0 + ty + 8 * i) * dld + y0 + tx] = f2bf(tile[tx][ty + 8 * i]);
}

// B_w = bf16(mW2) (coalesced copy, float4->us4) ; bias1024 = [mb1 | 0]
__global__ void prep_misc(const float* __restrict__ mW2, const float* __restrict__ mb1,
                          u16* __restrict__ B_w, float* __restrict__ bias1024)
{
    int i = blockIdx.x * 256 + threadIdx.x;            // [0, 65536)
    float4 v = ((const float4*)mW2)[i];
    us4 o = { f2bf(v.x), f2bf(v.y), f2bf(v.z), f2bf(v.w) };
    *(us4*)(B_w + (size_t)i * 4) = o;
    if (i < 1024) bias1024[i] = (i < 512) ? mb1[i] : 0.f;
}

// biasx[j] = ub1[j] + sum_l mb2[l] * uW1[512+l][j]   (one wave per j)
__global__ void prep_biasx(const float* __restrict__ ub1, const float* __restrict__ mb2,
                           const float* __restrict__ uW1, float* __restrict__ biasx)
{
    int wv = threadIdx.x >> 6, lane = threadIdx.x & 63;
    int j = blockIdx.x * 4 + wv;
    if (j >= 512) return;
    float s = 0.f;
    for (int l = lane; l < 512; l += 64)
        s += mb2[l] * uW1[(size_t)(512 + l) * 512 + j];
#pragma unroll
    for (int off = 32; off; off >>= 1) s += __shfl_xor(s, off, 64);
    if (lane == 0) biasx[j] = ub1[j] + s;
}

// Cast x (f32, M x 512) into cols [0,512) of XS (bf16, M x 1024)
__global__ void cast_x(const float* __restrict__ x, u16* __restrict__ XS, int total4)
{
    int i = blockIdx.x * 256 + threadIdx.x;
    if (i >= total4) return;
    int r = i >> 7, cg = i & 127;
    float4 v = ((const float4*)x)[i];
    us4 o = { f2bf(v.x), f2bf(v.y), f2bf(v.z), f2bf(v.w) };
    *(us4*)(XS + (size_t)r * 1024 + cg * 4) = o;
}

// ---------------------------------------------------------------------------
// GEMM: C[M,N] = A[M,K] (bf16, lda) @ BT[N][K] (bf16, ldb)
// K-loop = R11/R15 best-known-good, byte-identical (triple-buffered LDS,
// depth-2 counted vmcnt(4), single barrier/step, row-local XOR swizzle,
// 0 conflicts). ONE change vs R15: LDS-STAGED VECTORIZED EPILOGUE — acc is
// staged as bf16 into smem [128][132] (pad -> conflict-free), then each
// thread does 8x us8 (16B/lane) coalesced loads/stores for C, xres, lat —
// replacing 64 scalar 2B stores (+192 scalar loads in DORES) per thread.
// smem is one flat 48KB array; buffer bases computed inline (R16 compile
// fix: no static array of LDS pointers — addrspacecast in initializer).
// ---------------------------------------------------------------------------
template<int DOSILU, int DOBIAS, int DORES>
__global__ __launch_bounds__(256, 3)
void gemm_bt(const u16* __restrict__ A, int lda,
             const u16* __restrict__ Bt, int ldb,
             u16* __restrict__ Cb, int ldc,
             const float* __restrict__ bias,
             const u16* __restrict__ xres, const float* __restrict__ lat,
             const float* __restrict__ ub2v, int Nn, int M, int K)
{
    __shared__ __align__(16) u16 smem[24576];   // 48 KB flat
    // lA(buf) = smem + buf*4096 ; lB(buf) = smem + 12288 + buf*4096

    // T1: XCD-chunked bijective remap (m204)
    const int gx  = gridDim.x;
    const int nwg = gx * (int)gridDim.y;
    int flat = blockIdx.y * gx + blockIdx.x;
    {
        int q = nwg >> 3, r = nwg & 7;
        int xcd = flat & 7, jj = flat >> 3;
        flat = (xcd < r ? xcd * (q + 1) : r * (q + 1) + (xcd - r) * q) + jj;
    }
    const int m0 = (flat / gx) * 128;
    const int n0 = (flat % gx) * 128;

    const int tid  = threadIdx.x;
    const int wid  = tid >> 6;
    const int lane = tid & 63;
    const int lr   = lane & 15;
    const int h    = lane >> 4;
    const int wm   = (wid >> 1) * 64;
    const int wn   = (wid & 1) * 64;
    const int sw   = (lr >> 1) & 3;     // read-side swizzle (= (row>>1)&3)
    const int hs   = (h ^ sw) * 8;      // swizzled chunk offset (u16 units)

    f32x4 acc[4][4];
#pragma unroll
    for (int i = 0; i < 4; ++i)
#pragma unroll
        for (int j = 0; j < 4; ++j)
            acc[i][j] = (f32x4){0.f, 0.f, 0.f, 0.f};

    const int NT = K >> 5;

    const int csrc = ((lane & 3) ^ ((lane >> 3) & 3)) * 8;  // u16 offset in row

    auto stageA = [&](int t, int buf) {
#pragma unroll
        for (int q = 0; q < 2; ++q) {
            int gc = (wid * 2 + q) * 64 + lane;
            int r = gc >> 2;
            int grow = m0 + r; grow = grow < M ? grow : M - 1;
            const u16* src = A + (size_t)grow * lda + (t << 5) + csrc;
            gload_lds16(src, &smem[buf * 4096 + (wid * 2 + q) * 512]);
        }
    };
    auto stageB = [&](int t, int buf) {
#pragma unroll
        for (int q = 0; q < 2; ++q) {
            int gc = (wid * 2 + q) * 64 + lane;
            int r = gc >> 2;
            const u16* src = Bt + (size_t)(n0 + r) * ldb + (t << 5) + csrc;
            gload_lds16(src, &smem[12288 + buf * 4096 + (wid * 2 + q) * 512]);
        }
    };

    // prologue: tiles 0 and 1 in flight (8 outstanding VMEM/thread)
    stageA(0, 0); stageB(0, 0);
    stageA(1, 1); stageB(1, 1);

    for (int t = 0; t < NT; ++t) {
        const int buf = t % 3;
        if (t + 1 < NT) {
            asm volatile("s_waitcnt vmcnt(4)" ::: "memory");
        } else {
            asm volatile("s_waitcnt vmcnt(0)" ::: "memory");
        }
        __builtin_amdgcn_sched_barrier(0);
        __builtin_amdgcn_s_barrier();         // tile t visible; (t-1)%3 free
        __builtin_amdgcn_sched_barrier(0);

        if (t + 2 < NT) {
            stageA(t + 2, (t + 2) % 3);
            stageB(t + 2, (t + 2) % 3);
        }

        bf16x8 af[4], bfr[4];
#pragma unroll
        for (int i = 0; i < 4; ++i) {
            af[i]  = *(const bf16x8*)&smem[buf * 4096 + (wm + i * 16 + lr) * 32 + hs];
            bfr[i] = *(const bf16x8*)&smem[12288 + buf * 4096 + (wn + i * 16 + lr) * 32 + hs];
        }
#pragma unroll
        for (int i = 0; i < 4; ++i)
#pragma unroll
            for (int j = 0; j < 4; ++j)
                acc[i][j] = __builtin_amdgcn_mfma_f32_16x16x32_bf16(af[i], bfr[j], acc[i][j], 0, 0, 0);
        // no 2nd barrier: ds_reads retire before next step's barrier via the
        // compiler's lgkmcnt-before-MFMA; buffer reuse is 3 steps away.
    }

    float bv[4] = {0.f, 0.f, 0.f, 0.f};
    if (DOBIAS) {
#pragma unroll
        for (int j = 0; j < 4; ++j) bv[j] = bias[n0 + wn + j * 16 + lr];
    }

    // ---- epilogue: stage acc -> smem bf16 [128][132], then 16B/lane I/O ----
    // All K-loop smem reads retired (acc depends on them) and all
    // global_load_lds drained (vmcnt(0) at t=NT-1) -> safe to repurpose smem.
    __syncthreads();
    // D layout (m89-verified): col = lane&15, row = 4*(lane>>4) + reg
#pragma unroll
    for (int i = 0; i < 4; ++i)
#pragma unroll
        for (int rj = 0; rj < 4; ++rj) {
            int row = wm + i * 16 + 4 * h + rj;
#pragma unroll
            for (int j = 0; j < 4; ++j) {
                int col = wn + j * 16 + lr;
                float v = acc[i][j][rj] + bv[j];
                if (DOSILU) v = v * __builtin_amdgcn_rcpf(1.f + __expf(-v));
                smem[row * 132 + col] = f2bf(v);
            }
        }
    __syncthreads();

#pragma unroll
    for (int rr = 0; rr < 8; ++rr) {
        int row  = rr * 16 + (tid >> 4);
        int c8   = (tid & 15) * 8;
        int grow = m0 + row;
        if (grow >= M) continue;
        us8 sv = *(const us8*)&smem[row * 132 + c8];
        int gcol = n0 + c8;
        if (DORES) {
            int nn = grow % Nn;
            us8 xv = *(const us8*)&xres[(size_t)grow * 1024 + gcol];
            float4 l0 = *(const float4*)&lat[(size_t)nn * 512 + gcol];
            float4 l1 = *(const float4*)&lat[(size_t)nn * 512 + gcol + 4];
            float4 u0 = *(const float4*)&ub2v[gcol];
            float4 u1 = *(const float4*)&ub2v[gcol + 4];
            float lv[8] = {l0.x, l0.y, l0.z, l0.w, l1.x, l1.y, l1.z, l1.w};
            float uv[8] = {u0.x, u0.y, u0.z, u0.w, u1.x, u1.y, u1.z, u1.w};
            us8 o;
#pragma unroll
            for (int e = 0; e < 8; ++e)
                o[e] = f2bf(bf2f(sv[e]) + bf2f(xv[e]) + lv[e] + uv[e]);
            *(us8*)&Cb[(size_t)grow * ldc + gcol] = o;
        } else {
            *(us8*)&Cb[(size_t)grow * ldc + gcol] = sv;
        }
    }
}

// ---------------------------------------------------------------------------
// S[row] = (1/8) * sum_k silu(c_projb[row] + n_proj[b, knn[n,k]])
// (mb1 folded into c_proj via G1 bias.)  Writes cols 512.. of XS.
// ---------------------------------------------------------------------------
__global__ void gather_silu_mean(const u16* __restrict__ P, const int* __restrict__ knn,
                                 u16* __restrict__ XS, int Nn, int M)
{
    int wid = threadIdx.x >> 6, lane = threadIdx.x & 63;
    int row = blockIdx.x * 4 + wid;
    if (row >= M) return;
    int b = row / Nn, n = row - b * Nn;
    int c0 = lane * 8;

    int idx[8];
#pragma unroll
    for (int k = 0; k < 8; ++k) idx[k] = knn[n * 8 + k];

    us8 cu = *(const us8*)(P + (size_t)row * 1024 + c0);
    const u16* Pn = P + (size_t)b * Nn * 1024 + 512 + c0;
    us8 nb[8];
#pragma unroll
    for (int k = 0; k < 8; ++k) nb[k] = *(const us8*)(Pn + (size_t)idx[k] * 1024);

    float base[8], accv[8];
#pragma unroll
    for (int i = 0; i < 8; ++i) { base[i] = bf2f(cu[i]); accv[i] = 0.f; }

#pragma unroll
    for (int k = 0; k < 8; ++k)
#pragma unroll
        for (int i = 0; i < 8; ++i) {
            float pv = base[i] + bf2f(nb[k][i]);
            accv[i] += pv * __builtin_amdgcn_rcpf(1.f + __expf(-pv));
        }

    us8 o;
#pragma unroll
    for (int i = 0; i < 8; ++i) o[i] = f2bf(accv[i] * 0.125f);
    *(us8*)(XS + (size_t)row * 1024 + 512 + c0) = o;
}

// ---------------------------------------------------------------------------
// LN: reads bf16 pre-LN rows (Yt), writes f32 output Y.
// ---------------------------------------------------------------------------
__global__ void ln_fuse(const u16* __restrict__ Yt, float* __restrict__ Y,
                        const float* __restrict__ g, const float* __restrict__ bta,
                        int M)
{
    int wid = threadIdx.x >> 6, lane = threadIdx.x & 63;
    int row = blockIdx.x * 4 + wid;
    if (row >= M) return;
    int c0 = lane * 8;

    us8 u = *(const us8*)(Yt + (size_t)row * 512 + c0);
    float v[8];
#pragma unroll
    for (int i = 0; i < 8; ++i) v[i] = bf2f(u[i]);

    float s = 0.f;
#pragma unroll
    for (int i = 0; i < 8; ++i) s += v[i];
#pragma unroll
    for (int off = 32; off > 0; off >>= 1) s += __shfl_xor(s, off, 64);
    float mu = s * (1.f / 512.f);

    float q = 0.f;
#pragma unroll
    for (int i = 0; i < 8; ++i) { float d = v[i] - mu; q += d * d; }
#pragma unroll
    for (int off = 32; off > 0; off >>= 1) q += __shfl_xor(q, off, 64);
    float inv = rsqrtf(q * (1.f / 512.f) + 1e-5f);

    float* yr = Y + (size_t)row * 512 + c0;
#pragma unroll
    for (int i = 0; i < 8; ++i) yr[i] = (v[i] - mu) * inv * g[c0 + i] + bta[c0 + i];
}

extern "C" void kernel_launch(void* const* d_in, const int* in_sizes, int n_in,
                              void* d_out, int out_size, void* d_ws, size_t ws_size,
                              hipStream_t stream)
{
    const float* x   = (const float*)d_in[0];
    const float* lat = (const float*)d_in[1];
    const int*   knn = (const int*)d_in[2];
    const float* mW1 = (const float*)d_in[3];
    const float* mb1 = (const float*)d_in[4];
    const float* mW2 = (const float*)d_in[5];
    const float* mb2 = (const float*)d_in[6];
    const float* uW1 = (const float*)d_in[7];
    const float* ub1 = (const float*)d_in[8];
    const float* uW2 = (const float*)d_in[9];
    const float* ub2 = (const float*)d_in[10];
    const float* lng = (const float*)d_in[11];
    const float* lnb = (const float*)d_in[12];

    const int Nn = 10242;
    const int M  = 4 * Nn;       // 40968

    char* ws = (char*)d_ws;
    u16* BT1 = (u16*)ws; ws += (size_t)1024 * 512 * 2;
    u16* BTx = (u16*)ws; ws += (size_t)512 * 1024 * 2;
    u16* BT4 = (u16*)ws; ws += (size_t)512 * 512 * 2;
    u16* A_w = (u16*)ws; ws += (size_t)512 * 512 * 2;
    u16* B_w = (u16*)ws; ws += (size_t)512 * 512 * 2;
    float* bias1024 = (float*)ws; ws += 1024 * 4;
    float* biasx    = (float*)ws; ws += 512 * 4;
    u16* XS = (u16*)ws; ws += (size_t)M * 1024 * 2;    // [x_bf16 | S]
    u16* P  = (u16*)ws; ws += (size_t)M * 1024 * 2;    // [c_proj+mb1 | n_proj]
    u16* T  = (u16*)ws; ws += (size_t)M * 512 * 2;     // silu(u-pre)
    u16* Yt = P;                    // P dead after gather; reuse for pre-LN
    float* Y = (float*)d_out;

    const int MB = (M + 127) / 128;  // 321

    prep_transpose<<<dim3(16, 16, 5), 256, 0, stream>>>(mW1, uW2, uW1,
                                                        BT1, BT4, A_w, BTx);
    prep_misc<<<256, 256, 0, stream>>>(mW2, mb1, B_w, bias1024);
    prep_biasx<<<128, 256, 0, stream>>>(ub1, mb2, uW1, biasx);
    cast_x<<<(M * 512 / 4 + 255) / 256, 256, 0, stream>>>(x, XS, M * 512 / 4);

    // Wc^T -> BTx cols 512..1023  (M=512, N=512, K=512)
    gemm_bt<0, 0, 0><<<dim3(4, 4), 256, 0, stream>>>(
        A_w, 512, B_w, 512, BTx + 512, 1024,
        nullptr, nullptr, nullptr, nullptr, 0, 512, 512);

    // G1: P = x @ [mW1_top | mW1_bot] + [mb1 | 0]   (M x 1024, K=512)
    gemm_bt<0, 1, 0><<<dim3(8, MB), 256, 0, stream>>>(
        XS, 1024, BT1, 512, P, 1024,
        bias1024, nullptr, nullptr, nullptr, 0, M, 512);

    gather_silu_mean<<<(M + 3) / 4, 256, 0, stream>>>(P, knn, XS, Nn, M);

    // Gx: T = silu([x|S] @ [uW1_top; Wc] + biasx)   (M x 512, K=1024)
    gemm_bt<1, 1, 0><<<dim3(4, MB), 256, 0, stream>>>(
        XS, 1024, BTx, 1024, T, 512,
        biasx, nullptr, nullptr, nullptr, 0, M, 1024);

    // G4: Yt = bf16(T @ uW2 + x + lat + ub2)   (pre-LN, bf16 into P's buffer)
    gemm_bt<0, 0, 1><<<dim3(4, MB), 256, 0, stream>>>(
        T, 512, BT4, 512, Yt, 512,
        nullptr, XS, lat, ub2, Nn, M, 512);

    ln_fuse<<<(M + 3) / 4, 256, 0, stream>>>(Yt, Y, lng, lnb, M);
}

// Round 18
// 288.102 us; speedup vs baseline: 1.2409x; 1.0004x over previous
//
#include <hip/hip_runtime.h>
#include <hip/hip_bf16.h>
#include <cstdint>

typedef unsigned short u16;
typedef __attribute__((ext_vector_type(8))) __bf16 bf16x8;
typedef __attribute__((ext_vector_type(4))) float f32x4;
typedef __attribute__((ext_vector_type(8))) u16 us8;
typedef __attribute__((ext_vector_type(4))) u16 us4;

__device__ __forceinline__ float bf2f(u16 u) {
    return __uint_as_float(((unsigned int)u) << 16);
}
__device__ __forceinline__ u16 f2bf(float f) {
    unsigned int u = __float_as_uint(f);
    unsigned int r = (u + 0x7fffu + ((u >> 16) & 1u)) >> 16;
    return (u16)r;
}

__device__ __forceinline__ void gload_lds16(const void* src, void* dst) {
    __builtin_amdgcn_global_load_lds(
        (const __attribute__((address_space(1))) void*)src,
        (__attribute__((address_space(3))) void*)dst,
        16, 0, 0);
}

// ---------------------------------------------------------------------------
// Weight prep: LDS-tiled transpose+cast (coalesced both sides, R15-verified).
//  z=0: mW1[0:512,:]^T    -> BT1 rows 0-511   (ld 512)
//  z=1: mW1[512:1024,:]^T -> BT1 rows 512-1023(ld 512)
//  z=2: uW2^T             -> BT4              (ld 512)
//  z=3: uW1[512:1024,:]^T -> A_w              (ld 512)
//  z=4: uW1[0:512,:]^T    -> BTx cols 0-511   (ld 1024)
// ---------------------------------------------------------------------------
__global__ void prep_transpose(const float* __restrict__ mW1,
                               const float* __restrict__ uW2,
                               const float* __restrict__ uW1,
                               u16* __restrict__ BT1, u16* __restrict__ BT4,
                               u16* __restrict__ A_w, u16* __restrict__ BTx)
{
    __shared__ float tile[32][33];
    const float* src; u16* dst; int dld;
    switch (blockIdx.z) {
        case 0: src = mW1;                  dst = BT1;                  dld = 512;  break;
        case 1: src = mW1 + 512 * 512;      dst = BT1 + 512 * 512;      dld = 512;  break;
        case 2: src = uW2;                  dst = BT4;                  dld = 512;  break;
        case 3: src = uW1 + 512 * 512;      dst = A_w;                  dld = 512;  break;
        default: src = uW1;                 dst = BTx;                  dld = 1024; break;
    }
    int tx = threadIdx.x & 31, ty = threadIdx.x >> 5;      // 32 x 8
    int x0 = blockIdx.x * 32, y0 = blockIdx.y * 32;
#pragma unroll
    for (int i = 0; i < 4; ++i)
        tile[ty + 8 * i][tx] = src[(size_t)(y0 + ty + 8 * i) * 512 + x0 + tx];
    __syncthreads();
#pragma unroll
    for (int i = 0; i < 4; ++i)
        dst[(size_t)(x0 + ty + 8 * i) * dld + y0 + tx] = f2bf(tile[tx][ty + 8 * i]);
}

// B_w = bf16(mW2) (coalesced copy, float4->us4) ; bias1024 = [mb1 | 0]
__global__ void prep_misc(const float* __restrict__ mW2, const float* __restrict__ mb1,
                          u16* __restrict__ B_w, float* __restrict__ bias1024)
{
    int i = blockIdx.x * 256 + threadIdx.x;            // [0, 65536)
    float4 v = ((const float4*)mW2)[i];
    us4 o = { f2bf(v.x), f2bf(v.y), f2bf(v.z), f2bf(v.w) };
    *(us4*)(B_w + (size_t)i * 4) = o;
    if (i < 1024) bias1024[i] = (i < 512) ? mb1[i] : 0.f;
}

// biasx[j] = ub1[j] + sum_l mb2[l] * uW1[512+l][j]   (one wave per j)
__global__ void prep_biasx(const float* __restrict__ ub1, const float* __restrict__ mb2,
                           const float* __restrict__ uW1, float* __restrict__ biasx)
{
    int wv = threadIdx.x >> 6, lane = threadIdx.x & 63;
    int j = blockIdx.x * 4 + wv;
    if (j >= 512) return;
    float s = 0.f;
    for (int l = lane; l < 512; l += 64)
        s += mb2[l] * uW1[(size_t)(512 + l) * 512 + j];
#pragma unroll
    for (int off = 32; off; off >>= 1) s += __shfl_xor(s, off, 64);
    if (lane == 0) biasx[j] = ub1[j] + s;
}

// Cast x (f32, M x 512) into cols [0,512) of XS (bf16, M x 1024)
__global__ void cast_x(const float* __restrict__ x, u16* __restrict__ XS, int total4)
{
    int i = blockIdx.x * 256 + threadIdx.x;
    if (i >= total4) return;
    int r = i >> 7, cg = i & 127;
    float4 v = ((const float4*)x)[i];
    us4 o = { f2bf(v.x), f2bf(v.y), f2bf(v.z), f2bf(v.w) };
    *(us4*)(XS + (size_t)r * 1024 + cg * 4) = o;
}

// ---------------------------------------------------------------------------
// GEMM: C[M,N] = A[M,K] (bf16, lda) @ BT[N][K] (bf16, ldb)
// R17 best-known-good (288 us total), byte-identical except ONE change:
// T5 s_setprio(1)/(0) around the MFMA cluster. Mechanism: the single-barrier
// loop lets resident waves occupy different roles (staging VMEM issue vs
// ds_read vs MFMA) between barriers -- setprio biases the CU scheduler
// toward MFMA-entering waves (catalog T5 prerequisite = role diversity;
// m190's null was on a 2-barrier lockstep loop).
// ---------------------------------------------------------------------------
template<int DOSILU, int DOBIAS, int DORES>
__global__ __launch_bounds__(256, 3)
void gemm_bt(const u16* __restrict__ A, int lda,
             const u16* __restrict__ Bt, int ldb,
             u16* __restrict__ Cb, int ldc,
             const float* __restrict__ bias,
             const u16* __restrict__ xres, const float* __restrict__ lat,
             const float* __restrict__ ub2v, int Nn, int M, int K)
{
    __shared__ __align__(16) u16 smem[24576];   // 48 KB flat
    // lA(buf) = smem + buf*4096 ; lB(buf) = smem + 12288 + buf*4096

    // T1: XCD-chunked bijective remap (m204)
    const int gx  = gridDim.x;
    const int nwg = gx * (int)gridDim.y;
    int flat = blockIdx.y * gx + blockIdx.x;
    {
        int q = nwg >> 3, r = nwg & 7;
        int xcd = flat & 7, jj = flat >> 3;
        flat = (xcd < r ? xcd * (q + 1) : r * (q + 1) + (xcd - r) * q) + jj;
    }
    const int m0 = (flat / gx) * 128;
    const int n0 = (flat % gx) * 128;

    const int tid  = threadIdx.x;
    const int wid  = tid >> 6;
    const int lane = tid & 63;
    const int lr   = lane & 15;
    const int h    = lane >> 4;
    const int wm   = (wid >> 1) * 64;
    const int wn   = (wid & 1) * 64;
    const int sw   = (lr >> 1) & 3;     // read-side swizzle (= (row>>1)&3)
    const int hs   = (h ^ sw) * 8;      // swizzled chunk offset (u16 units)

    f32x4 acc[4][4];
#pragma unroll
    for (int i = 0; i < 4; ++i)
#pragma unroll
        for (int j = 0; j < 4; ++j)
            acc[i][j] = (f32x4){0.f, 0.f, 0.f, 0.f};

    const int NT = K >> 5;

    const int csrc = ((lane & 3) ^ ((lane >> 3) & 3)) * 8;  // u16 offset in row

    auto stageA = [&](int t, int buf) {
#pragma unroll
        for (int q = 0; q < 2; ++q) {
            int gc = (wid * 2 + q) * 64 + lane;
            int r = gc >> 2;
            int grow = m0 + r; grow = grow < M ? grow : M - 1;
            const u16* src = A + (size_t)grow * lda + (t << 5) + csrc;
            gload_lds16(src, &smem[buf * 4096 + (wid * 2 + q) * 512]);
        }
    };
    auto stageB = [&](int t, int buf) {
#pragma unroll
        for (int q = 0; q < 2; ++q) {
            int gc = (wid * 2 + q) * 64 + lane;
            int r = gc >> 2;
            const u16* src = Bt + (size_t)(n0 + r) * ldb + (t << 5) + csrc;
            gload_lds16(src, &smem[12288 + buf * 4096 + (wid * 2 + q) * 512]);
        }
    };

    // prologue: tiles 0 and 1 in flight (8 outstanding VMEM/thread)
    stageA(0, 0); stageB(0, 0);
    stageA(1, 1); stageB(1, 1);

    for (int t = 0; t < NT; ++t) {
        const int buf = t % 3;
        if (t + 1 < NT) {
            asm volatile("s_waitcnt vmcnt(4)" ::: "memory");
        } else {
            asm volatile("s_waitcnt vmcnt(0)" ::: "memory");
        }
        __builtin_amdgcn_sched_barrier(0);
        __builtin_amdgcn_s_barrier();         // tile t visible; (t-1)%3 free
        __builtin_amdgcn_sched_barrier(0);

        if (t + 2 < NT) {
            stageA(t + 2, (t + 2) % 3);
            stageB(t + 2, (t + 2) % 3);
        }

        bf16x8 af[4], bfr[4];
#pragma unroll
        for (int i = 0; i < 4; ++i) {
            af[i]  = *(const bf16x8*)&smem[buf * 4096 + (wm + i * 16 + lr) * 32 + hs];
            bfr[i] = *(const bf16x8*)&smem[12288 + buf * 4096 + (wn + i * 16 + lr) * 32 + hs];
        }
        __builtin_amdgcn_s_setprio(1);
#pragma unroll
        for (int i = 0; i < 4; ++i)
#pragma unroll
            for (int j = 0; j < 4; ++j)
                acc[i][j] = __builtin_amdgcn_mfma_f32_16x16x32_bf16(af[i], bfr[j], acc[i][j], 0, 0, 0);
        __builtin_amdgcn_s_setprio(0);
        // no 2nd barrier: ds_reads retire before next step's barrier via the
        // compiler's lgkmcnt-before-MFMA; buffer reuse is 3 steps away.
    }

    float bv[4] = {0.f, 0.f, 0.f, 0.f};
    if (DOBIAS) {
#pragma unroll
        for (int j = 0; j < 4; ++j) bv[j] = bias[n0 + wn + j * 16 + lr];
    }

    // ---- epilogue: stage acc -> smem bf16 [128][132], then 16B/lane I/O ----
    __syncthreads();
    // D layout (m89-verified): col = lane&15, row = 4*(lane>>4) + reg
#pragma unroll
    for (int i = 0; i < 4; ++i)
#pragma unroll
        for (int rj = 0; rj < 4; ++rj) {
            int row = wm + i * 16 + 4 * h + rj;
#pragma unroll
            for (int j = 0; j < 4; ++j) {
                int col = wn + j * 16 + lr;
                float v = acc[i][j][rj] + bv[j];
                if (DOSILU) v = v * __builtin_amdgcn_rcpf(1.f + __expf(-v));
                smem[row * 132 + col] = f2bf(v);
            }
        }
    __syncthreads();

#pragma unroll
    for (int rr = 0; rr < 8; ++rr) {
        int row  = rr * 16 + (tid >> 4);
        int c8   = (tid & 15) * 8;
        int grow = m0 + row;
        if (grow >= M) continue;
        us8 sv = *(const us8*)&smem[row * 132 + c8];
        int gcol = n0 + c8;
        if (DORES) {
            int nn = grow % Nn;
            us8 xv = *(const us8*)&xres[(size_t)grow * 1024 + gcol];
            float4 l0 = *(const float4*)&lat[(size_t)nn * 512 + gcol];
            float4 l1 = *(const float4*)&lat[(size_t)nn * 512 + gcol + 4];
            float4 u0 = *(const float4*)&ub2v[gcol];
            float4 u1 = *(const float4*)&ub2v[gcol + 4];
            float lv[8] = {l0.x, l0.y, l0.z, l0.w, l1.x, l1.y, l1.z, l1.w};
            float uv[8] = {u0.x, u0.y, u0.z, u0.w, u1.x, u1.y, u1.z, u1.w};
            us8 o;
#pragma unroll
            for (int e = 0; e < 8; ++e)
                o[e] = f2bf(bf2f(sv[e]) + bf2f(xv[e]) + lv[e] + uv[e]);
            *(us8*)&Cb[(size_t)grow * ldc + gcol] = o;
        } else {
            *(us8*)&Cb[(size_t)grow * ldc + gcol] = sv;
        }
    }
}

// ---------------------------------------------------------------------------
// S[row] = (1/8) * sum_k silu(c_projb[row] + n_proj[b, knn[n,k]])
// (mb1 folded into c_proj via G1 bias.)  Writes cols 512.. of XS.
// ---------------------------------------------------------------------------
__global__ void gather_silu_mean(const u16* __restrict__ P, const int* __restrict__ knn,
                                 u16* __restrict__ XS, int Nn, int M)
{
    int wid = threadIdx.x >> 6, lane = threadIdx.x & 63;
    int row = blockIdx.x * 4 + wid;
    if (row >= M) return;
    int b = row / Nn, n = row - b * Nn;
    int c0 = lane * 8;

    int idx[8];
#pragma unroll
    for (int k = 0; k < 8; ++k) idx[k] = knn[n * 8 + k];

    us8 cu = *(const us8*)(P + (size_t)row * 1024 + c0);
    const u16* Pn = P + (size_t)b * Nn * 1024 + 512 + c0;
    us8 nb[8];
#pragma unroll
    for (int k = 0; k < 8; ++k) nb[k] = *(const us8*)(Pn + (size_t)idx[k] * 1024);

    float base[8], accv[8];
#pragma unroll
    for (int i = 0; i < 8; ++i) { base[i] = bf2f(cu[i]); accv[i] = 0.f; }

#pragma unroll
    for (int k = 0; k < 8; ++k)
#pragma unroll
        for (int i = 0; i < 8; ++i) {
            float pv = base[i] + bf2f(nb[k][i]);
            accv[i] += pv * __builtin_amdgcn_rcpf(1.f + __expf(-pv));
        }

    us8 o;
#pragma unroll
    for (int i = 0; i < 8; ++i) o[i] = f2bf(accv[i] * 0.125f);
    *(us8*)(XS + (size_t)row * 1024 + 512 + c0) = o;
}

// ---------------------------------------------------------------------------
// LN: reads bf16 pre-LN rows (Yt), writes f32 output Y.
// ---------------------------------------------------------------------------
__global__ void ln_fuse(const u16* __restrict__ Yt, float* __restrict__ Y,
                        const float* __restrict__ g, const float* __restrict__ bta,
                        int M)
{
    int wid = threadIdx.x >> 6, lane = threadIdx.x & 63;
    int row = blockIdx.x * 4 + wid;
    if (row >= M) return;
    int c0 = lane * 8;

    us8 u = *(const us8*)(Yt + (size_t)row * 512 + c0);
    float v[8];
#pragma unroll
    for (int i = 0; i < 8; ++i) v[i] = bf2f(u[i]);

    float s = 0.f;
#pragma unroll
    for (int i = 0; i < 8; ++i) s += v[i];
#pragma unroll
    for (int off = 32; off > 0; off >>= 1) s += __shfl_xor(s, off, 64);
    float mu = s * (1.f / 512.f);

    float q = 0.f;
#pragma unroll
    for (int i = 0; i < 8; ++i) { float d = v[i] - mu; q += d * d; }
#pragma unroll
    for (int off = 32; off > 0; off >>= 1) q += __shfl_xor(q, off, 64);
    float inv = rsqrtf(q * (1.f / 512.f) + 1e-5f);

    float* yr = Y + (size_t)row * 512 + c0;
#pragma unroll
    for (int i = 0; i < 8; ++i) yr[i] = (v[i] - mu) * inv * g[c0 + i] + bta[c0 + i];
}

extern "C" void kernel_launch(void* const* d_in, const int* in_sizes, int n_in,
                              void* d_out, int out_size, void* d_ws, size_t ws_size,
                              hipStream_t stream)
{
    const float* x   = (const float*)d_in[0];
    const float* lat = (const float*)d_in[1];
    const int*   knn = (const int*)d_in[2];
    const float* mW1 = (const float*)d_in[3];
    const float* mb1 = (const float*)d_in[4];
    const float* mW2 = (const float*)d_in[5];
    const float* mb2 = (const float*)d_in[6];
    const float* uW1 = (const float*)d_in[7];
    const float* ub1 = (const float*)d_in[8];
    const float* uW2 = (const float*)d_in[9];
    const float* ub2 = (const float*)d_in[10];
    const float* lng = (const float*)d_in[11];
    const float* lnb = (const float*)d_in[12];

    const int Nn = 10242;
    const int M  = 4 * Nn;       // 40968

    char* ws = (char*)d_ws;
    u16* BT1 = (u16*)ws; ws += (size_t)1024 * 512 * 2;
    u16* BTx = (u16*)ws; ws += (size_t)512 * 1024 * 2;
    u16* BT4 = (u16*)ws; ws += (size_t)512 * 512 * 2;
    u16* A_w = (u16*)ws; ws += (size_t)512 * 512 * 2;
    u16* B_w = (u16*)ws; ws += (size_t)512 * 512 * 2;
    float* bias1024 = (float*)ws; ws += 1024 * 4;
    float* biasx    = (float*)ws; ws += 512 * 4;
    u16* XS = (u16*)ws; ws += (size_t)M * 1024 * 2;    // [x_bf16 | S]
    u16* P  = (u16*)ws; ws += (size_t)M * 1024 * 2;    // [c_proj+mb1 | n_proj]
    u16* T  = (u16*)ws; ws += (size_t)M * 512 * 2;     // silu(u-pre)
    u16* Yt = P;                    // P dead after gather; reuse for pre-LN
    float* Y = (float*)d_out;

    const int MB = (M + 127) / 128;  // 321

    prep_transpose<<<dim3(16, 16, 5), 256, 0, stream>>>(mW1, uW2, uW1,
                                                        BT1, BT4, A_w, BTx);
    prep_misc<<<256, 256, 0, stream>>>(mW2, mb1, B_w, bias1024);
    prep_biasx<<<128, 256, 0, stream>>>(ub1, mb2, uW1, biasx);
    cast_x<<<(M * 512 / 4 + 255) / 256, 256, 0, stream>>>(x, XS, M * 512 / 4);

    // Wc^T -> BTx cols 512..1023  (M=512, N=512, K=512)
    gemm_bt<0, 0, 0><<<dim3(4, 4), 256, 0, stream>>>(
        A_w, 512, B_w, 512, BTx + 512, 1024,
        nullptr, nullptr, nullptr, nullptr, 0, 512, 512);

    // G1: P = x @ [mW1_top | mW1_bot] + [mb1 | 0]   (M x 1024, K=512)
    gemm_bt<0, 1, 0><<<dim3(8, MB), 256, 0, stream>>>(
        XS, 1024, BT1, 512, P, 1024,
        bias1024, nullptr, nullptr, nullptr, 0, M, 512);

    gather_silu_mean<<<(M + 3) / 4, 256, 0, stream>>>(P, knn, XS, Nn, M);

    // Gx: T = silu([x|S] @ [uW1_top; Wc] + biasx)   (M x 512, K=1024)
    gemm_bt<1, 1, 0><<<dim3(4, MB), 256, 0, stream>>>(
        XS, 1024, BTx, 1024, T, 512,
        biasx, nullptr, nullptr, nullptr, 0, M, 1024);

    // G4: Yt = bf16(T @ uW2 + x + lat + ub2)   (pre-LN, bf16 into P's buffer)
    gemm_bt<0, 0, 1><<<dim3(4, MB), 256, 0, stream>>>(
        T, 512, BT4, 512, Yt, 512,
        nullptr, XS, lat, ub2, Nn, M, 512);

    ln_fuse<<<(M + 3) / 4, 256, 0, stream>>>(Yt, Y, lng, lnb, M);
}